// Round 7
// baseline (336.008 us; speedup 1.0000x reference)
//
#include <hip/hip_runtime.h>

// uDTW forward DP, R15: K=64 (23 phases vs 39) + lgkm-only barrier.
//
// R14 post-mortem: stripping ~150 inst/phase (VGPR 100->72) left per-phase
// cost EXACTLY at R9's 7.4k cycles -> phase time is fixed-overhead-bound:
// VALU issue ~2.6k (VALUBusy 35%/active CU), 32-step chain ~1.2k, the rest
// (~4.5k) is barrier drain + skew + LDS latency. Model: T = PHASES*(F + n*c).
// So: halve PHASES (K=64, NB=16, wave w active B in [w, w+8], p = B + w,
// 23 phases) and shave F (s_waitcnt lgkmcnt(0) + raw s_barrier -- global
// prefetches are private regs and may legally stay in flight across the
// barrier; only LDS publishes need draining).
//
// Register budget (512thr -> 128-reg cap, R11/R12 lesson):
//  - D window 17 quads (68 regs), dies into f/g at the funnel.
//  - funnel as unrolled arrays (f[68] -> x[65] -> g[64]); f dies as g fills.
//  - neighbor pairs: 32 float4 read in 8 groups of 4, one group ahead.
//  - prefetch split: r0..r8 after step 31, r9..r16 after step 55 (dead regs).
// Peak live ~120. Checks: WRITE_SIZE ~2KB = no spill; conflicts 0 (R9 layout).

constexpr int N = 512;
constexpr int M = 512;
constexpr int BATCH = 32;
constexpr int NM = N + M;                  // 1024; diags d = 2..NM
constexpr int K = 64;                      // diagonals per burst
constexpr int NB = 16;                     // bursts cover d = 2..1025
constexpr int PHASES = 23;                 // p = B + w; B in [w, w+8]
constexpr float NL2E = -1.4426950408889634f;   // -log2(e)
constexpr float NLN2 = -0.6931471805599453f;   // -ln(2)
constexpr float EPS  = 1e-30f;

__device__ __forceinline__ float lane_shr1_or(float oldv, float x) {
  // lane n gets lane n-1's x; lane 0 keeps oldv (bound_ctrl=false).
  return __int_as_float(__builtin_amdgcn_update_dpp(
      __float_as_int(oldv), __float_as_int(x), 0x138, 0xf, 0xf, false));
}
__device__ __forceinline__ int qclamp(int q) {
  return q < 0 ? 0 : (q > 127 ? 127 : q);
}

__global__ __launch_bounds__(512, 2)
void softdtw_fwd(const float* __restrict__ D,
                 const float* __restrict__ Sig,
                 float* __restrict__ out) {
  const int b = blockIdx.x;
  const int t = threadIdx.x;           // row r = t, cell i = t+1
  const int w = t >> 6;                // wave 0..7
  const float4* Drow4 = (const float4*)(D + ((size_t)b * N + t) * M);

  // edge[w][64 + c] = (exp(-R), NL2E*Ddiag) of row 64w+63 at column c.
  // Lane-63-final invariant: later (higher-t) writes to a column always
  // precede any consumer read of it (verified for K=64: producer's
  // concurrent-phase writes target columns >= read_base + 65).
  __shared__ float2 edge[8][640];
  __shared__ __align__(16) float zpad[128];  // zero source for w==0 (32 quads)
  for (int idx = t; idx < 8 * 640; idx += 512)
    ((float2*)edge)[idx] = make_float2(0.f, 0.f);
  if (t < 128) zpad[t] = 0.f;

  // carried state: own cell at d-1, neighbor (i-1) at d-2 (D pre-scaled)
  float eSelf = 0.f, dSelfL = 0.f;
  float eN2 = (t == 0) ? 1.f : 0.f, dN2L = 0.f;   // R[0,0]=0 -> e=1

  const int Bl = w, Bh = w + 8;        // active bursts for this wave

  // current-burst D window: 17 quads covering floats [4*((64B-t)>>2), +68)
  float4 r0,r1,r2,r3,r4,r5,r6,r7,r8,r9,r10,r11,r12,r13,r14,r15,r16;
  {
    const int q = (K * Bl - t) >> 2;
    r0 = Drow4[qclamp(q + 0)];  r1 = Drow4[qclamp(q + 1)];
    r2 = Drow4[qclamp(q + 2)];  r3 = Drow4[qclamp(q + 3)];
    r4 = Drow4[qclamp(q + 4)];  r5 = Drow4[qclamp(q + 5)];
    r6 = Drow4[qclamp(q + 6)];  r7 = Drow4[qclamp(q + 7)];
    r8 = Drow4[qclamp(q + 8)];  r9 = Drow4[qclamp(q + 9)];
    r10 = Drow4[qclamp(q + 10)]; r11 = Drow4[qclamp(q + 11)];
    r12 = Drow4[qclamp(q + 12)]; r13 = Drow4[qclamp(q + 13)];
    r14 = Drow4[qclamp(q + 14)]; r15 = Drow4[qclamp(q + 15)];
    r16 = Drow4[qclamp(q + 16)];
  }
  __syncthreads();

  for (int p = 0; p < PHASES; ++p) {
    const int B = p - w;
    const int Bn = B + 1;
    const bool dopre = (Bn >= Bl) && (Bn <= Bh);   // wave-uniform

    if (B >= Bl && B <= Bh) {
      const int d0 = 2 + B * K;
      const int c0 = K * B - t;        // column base (c = j-1); in [-63, 512]

      // ---- neighbor boundary plane pointer (wave-uniform broadcasts;
      // w==0 reads the zeroed pad). 32 float4 = 64 (E,D) pairs.
      const float4* ep = (w > 0)
          ? (const float4*)&edge[w - 1][64 + K * (B - w)]
          : (const float4*)zpad;

      // group a (steps 0..7): LDS latency hides under the funnel
      const float4 na0 = ep[0], na1 = ep[1], na2 = ep[2], na3 = ep[3];

      // ---- funnel align by s = c0 & 3: g[e] = D[c0 + e], e in [0,64)
      const int s = c0 & 3;
      const bool s2 = (s & 2) != 0, s1b = (s & 1) != 0;
      float f[68];
#define UNP(i, R) f[4*(i)] = (R).x; f[4*(i)+1] = (R).y; \
                  f[4*(i)+2] = (R).z; f[4*(i)+3] = (R).w;
      UNP(0, r0)  UNP(1, r1)  UNP(2, r2)  UNP(3, r3)  UNP(4, r4)
      UNP(5, r5)  UNP(6, r6)  UNP(7, r7)  UNP(8, r8)  UNP(9, r9)
      UNP(10, r10) UNP(11, r11) UNP(12, r12) UNP(13, r13)
      UNP(14, r14) UNP(15, r15) UNP(16, r16)
#undef UNP
      float g[64];
      {
        float x[65];
#pragma unroll
        for (int e = 0; e < 65; ++e) x[e] = s2 ? f[e + 2] : f[e];
#pragma unroll
        for (int e = 0; e < 64; ++e) g[e] = s1b ? x[e + 1] : x[e];
      }

      float2* eput = &edge[w][64 + c0];   // write-once publish (8B stride)

#define STEP(kk, NE, ND)                                                       \
      {                                                                        \
        const int c = c0 + (kk);                                               \
        const bool valid = ((unsigned)c) < 512u;                               \
        const float ddL = g[kk] * NL2E;                                        \
        const float ddLm = valid ? ddL : -1e30f;                               \
        const float sE = lane_shr1_or((NE), eSelf);                            \
        const float sD = lane_shr1_or((ND), dSelfL);                           \
        const float e0 = eN2, e2 = eSelf;                                      \
        const float s02 = (e0 + e2) + EPS;                                     \
        const float sum = s02 + sE;                                            \
        const float inv = __builtin_amdgcn_rcpf(sum);                          \
        const float numL = fmaf(e0, dN2L, fmaf(sE, sD, e2 * dSelfL));          \
        const float rr = fmaf(inv, numL, ddLm);                                \
        const float newE = __builtin_amdgcn_exp2f(rr);                         \
        if (d0 + (kk) == NM && t == N - 1) {                                   \
          const float* Sb = Sig + (size_t)b * N * M;                           \
          const float sgA = Sb[(size_t)(N - 1) * M + (M - 1)];                 \
          const float sg0 = Sb[(size_t)(N - 2) * M + (M - 2)];                 \
          const float sg1 = Sb[(size_t)(N - 2) * M + (M - 1)];                 \
          const float sg2 = Sb[(size_t)(N - 1) * M + (M - 2)];                 \
          out[b] = rr * NLN2;                                                  \
          out[BATCH + b] = sgA + inv * (e0 * sg0 + sE * sg1 + e2 * sg2);       \
        }                                                                      \
        eN2 = sE; dN2L = sD;                                                   \
        eSelf = newE; dSelfL = ddL;                                            \
        eput[kk] = make_float2(newE, ddL);                                     \
      }

      // group b (steps 8..15) read one group ahead
      const float4 nb0 = ep[4], nb1 = ep[5], nb2 = ep[6], nb3 = ep[7];

      STEP(0,  na0.x, na0.y)  STEP(1,  na0.z, na0.w)
      STEP(2,  na1.x, na1.y)  STEP(3,  na1.z, na1.w)
      STEP(4,  na2.x, na2.y)  STEP(5,  na2.z, na2.w)
      STEP(6,  na3.x, na3.y)  STEP(7,  na3.z, na3.w)

      const float4 nc0 = ep[8], nc1 = ep[9], nc2 = ep[10], nc3 = ep[11];

      STEP(8,  nb0.x, nb0.y)  STEP(9,  nb0.z, nb0.w)
      STEP(10, nb1.x, nb1.y)  STEP(11, nb1.z, nb1.w)
      STEP(12, nb2.x, nb2.y)  STEP(13, nb2.z, nb2.w)
      STEP(14, nb3.x, nb3.y)  STEP(15, nb3.z, nb3.w)

      const float4 nd0 = ep[12], nd1 = ep[13], nd2 = ep[14], nd3 = ep[15];

      STEP(16, nc0.x, nc0.y)  STEP(17, nc0.z, nc0.w)
      STEP(18, nc1.x, nc1.y)  STEP(19, nc1.z, nc1.w)
      STEP(20, nc2.x, nc2.y)  STEP(21, nc2.z, nc2.w)
      STEP(22, nc3.x, nc3.y)  STEP(23, nc3.z, nc3.w)

      const float4 ne0 = ep[16], ne1 = ep[17], ne2 = ep[18], ne3 = ep[19];

      STEP(24, nd0.x, nd0.y)  STEP(25, nd0.z, nd0.w)
      STEP(26, nd1.x, nd1.y)  STEP(27, nd1.z, nd1.w)
      STEP(28, nd2.x, nd2.y)  STEP(29, nd2.z, nd2.w)
      STEP(30, nd3.x, nd3.y)  STEP(31, nd3.z, nd3.w)

      // ---- prefetch half A: r0..r8 are long dead (funnel); 32 steps +
      // barrier of hiding distance before next phase's funnel reads them.
      if (dopre) {
        const int q = (K * Bn - t) >> 2;
        r0 = Drow4[qclamp(q + 0)];  r1 = Drow4[qclamp(q + 1)];
        r2 = Drow4[qclamp(q + 2)];  r3 = Drow4[qclamp(q + 3)];
        r4 = Drow4[qclamp(q + 4)];  r5 = Drow4[qclamp(q + 5)];
        r6 = Drow4[qclamp(q + 6)];  r7 = Drow4[qclamp(q + 7)];
        r8 = Drow4[qclamp(q + 8)];
      }

      const float4 nf0 = ep[20], nf1 = ep[21], nf2 = ep[22], nf3 = ep[23];

      STEP(32, ne0.x, ne0.y)  STEP(33, ne0.z, ne0.w)
      STEP(34, ne1.x, ne1.y)  STEP(35, ne1.z, ne1.w)
      STEP(36, ne2.x, ne2.y)  STEP(37, ne2.z, ne2.w)
      STEP(38, ne3.x, ne3.y)  STEP(39, ne3.z, ne3.w)

      const float4 ng0 = ep[24], ng1 = ep[25], ng2 = ep[26], ng3 = ep[27];

      STEP(40, nf0.x, nf0.y)  STEP(41, nf0.z, nf0.w)
      STEP(42, nf1.x, nf1.y)  STEP(43, nf1.z, nf1.w)
      STEP(44, nf2.x, nf2.y)  STEP(45, nf2.z, nf2.w)
      STEP(46, nf3.x, nf3.y)  STEP(47, nf3.z, nf3.w)

      const float4 nh0 = ep[28], nh1 = ep[29], nh2 = ep[30], nh3 = ep[31];

      STEP(48, ng0.x, ng0.y)  STEP(49, ng0.z, ng0.w)
      STEP(50, ng1.x, ng1.y)  STEP(51, ng1.z, ng1.w)
      STEP(52, ng2.x, ng2.y)  STEP(53, ng2.z, ng2.w)
      STEP(54, ng3.x, ng3.y)  STEP(55, ng3.z, ng3.w)

      // ---- prefetch half B: loads may stay in flight across the barrier
      // (lgkm-only barrier below); waits land at next phase's funnel.
      if (dopre) {
        const int q = (K * Bn - t) >> 2;
        r9 = Drow4[qclamp(q + 9)];   r10 = Drow4[qclamp(q + 10)];
        r11 = Drow4[qclamp(q + 11)]; r12 = Drow4[qclamp(q + 12)];
        r13 = Drow4[qclamp(q + 13)]; r14 = Drow4[qclamp(q + 14)];
        r15 = Drow4[qclamp(q + 15)]; r16 = Drow4[qclamp(q + 16)];
      }

      STEP(56, nh0.x, nh0.y)  STEP(57, nh0.z, nh0.w)
      STEP(58, nh1.x, nh1.y)  STEP(59, nh1.z, nh1.w)
      STEP(60, nh2.x, nh2.y)  STEP(61, nh2.z, nh2.w)
      STEP(62, nh3.x, nh3.y)  STEP(63, nh3.z, nh3.w)
#undef STEP
    } else if (dopre) {
      // pipeline-fill: wave becomes active next phase; load its first burst
      const int q = (K * Bn - t) >> 2;
      r0 = Drow4[qclamp(q + 0)];  r1 = Drow4[qclamp(q + 1)];
      r2 = Drow4[qclamp(q + 2)];  r3 = Drow4[qclamp(q + 3)];
      r4 = Drow4[qclamp(q + 4)];  r5 = Drow4[qclamp(q + 5)];
      r6 = Drow4[qclamp(q + 6)];  r7 = Drow4[qclamp(q + 7)];
      r8 = Drow4[qclamp(q + 8)];  r9 = Drow4[qclamp(q + 9)];
      r10 = Drow4[qclamp(q + 10)]; r11 = Drow4[qclamp(q + 11)];
      r12 = Drow4[qclamp(q + 12)]; r13 = Drow4[qclamp(q + 13)];
      r14 = Drow4[qclamp(q + 14)]; r15 = Drow4[qclamp(q + 15)];
      r16 = Drow4[qclamp(q + 16)];
    }

    // lgkm-only barrier: LDS publishes drained; private global prefetches
    // legally stay in flight across the barrier (counted-vmcnt pattern).
    asm volatile("s_waitcnt lgkmcnt(0)" ::: "memory");
    __builtin_amdgcn_s_barrier();
  }
}

extern "C" void kernel_launch(void* const* d_in, const int* in_sizes, int n_in,
                              void* d_out, int out_size, void* d_ws, size_t ws_size,
                              hipStream_t stream) {
  const float* D   = (const float*)d_in[0];
  const float* Sig = (const float*)d_in[1];
  float* out = (float*)d_out;
  softdtw_fwd<<<dim3(BATCH), dim3(512), 0, stream>>>(D, Sig, out);
}

// Round 8
// 172.152 us; speedup vs baseline: 1.9518x; 1.9518x over previous
//
#include <hip/hip_runtime.h>

// uDTW forward DP, R16: K=64 / 23-phase / lgkm-only barrier (R15 structure,
// PROVEN CORRECT: absmax 0.0) with the funnel re-done as explicit scalars.
//
// R15 post-mortem: f[68]/x[65]/g[64] arrays defeated SROA -> localMem
// (WRITE_SIZE 8.5MB of scratch, FETCH +2.9MB, VALUBusy 1.7%). The K=64
// schedule itself was fine. R14 proved explicit-scalar funnels compile to
// clean registers (72 VGPR). So: two R14-style scalar funnel halves:
//   funnel A: quads r0..r8  -> g0..g31  (floats c0+0 .. c0+31)
//   funnel B: quads r8..r16 -> j0..j31  (floats c0+32 .. c0+63)
// Seam verified: g31 = s1b ? x32 : x31, x32 = s2?f34:f32 (r8.z/r8.x);
// funnel B's y0 recomputes exactly x32.
// Prefetch: next burst r0..r7 after funnel A (dead), r8..r16 after funnel B;
// >=32 steps + barrier of hiding distance; loads cross the lgkm-only barrier.
// Neighbor plane: 32 wave-uniform float4 broadcasts, one 4-quad group ahead.
// Peak live ~125 regs. Checks: WRITE_SIZE ~2KB (no scratch), conflicts 0.

constexpr int N = 512;
constexpr int M = 512;
constexpr int BATCH = 32;
constexpr int NM = N + M;                  // 1024; diags d = 2..NM
constexpr int K = 64;                      // diagonals per burst
constexpr int NB = 16;                     // bursts cover d = 2..1025
constexpr int PHASES = 23;                 // p = B + w; B in [w, w+8]
constexpr float NL2E = -1.4426950408889634f;   // -log2(e)
constexpr float NLN2 = -0.6931471805599453f;   // -ln(2)
constexpr float EPS  = 1e-30f;

__device__ __forceinline__ float lane_shr1_or(float oldv, float x) {
  // lane n gets lane n-1's x; lane 0 keeps oldv (bound_ctrl=false).
  return __int_as_float(__builtin_amdgcn_update_dpp(
      __float_as_int(oldv), __float_as_int(x), 0x138, 0xf, 0xf, false));
}
__device__ __forceinline__ int qclamp(int q) {
  return q < 0 ? 0 : (q > 127 ? 127 : q);
}

__global__ __launch_bounds__(512, 2)
void softdtw_fwd(const float* __restrict__ D,
                 const float* __restrict__ Sig,
                 float* __restrict__ out) {
  const int b = blockIdx.x;
  const int t = threadIdx.x;           // row r = t, cell i = t+1
  const int w = t >> 6;                // wave 0..7
  const float4* Drow4 = (const float4*)(D + ((size_t)b * N + t) * M);

  // edge[w][64 + c] = (exp(-R), NL2E*Ddiag) of row 64w+63 at column c.
  __shared__ float2 edge[8][640];
  __shared__ __align__(16) float zpad[128];  // zero source for w==0 (32 quads)
  for (int idx = t; idx < 8 * 640; idx += 512)
    ((float2*)edge)[idx] = make_float2(0.f, 0.f);
  if (t < 128) zpad[t] = 0.f;

  // carried state: own cell at d-1, neighbor (i-1) at d-2 (D pre-scaled)
  float eSelf = 0.f, dSelfL = 0.f;
  float eN2 = (t == 0) ? 1.f : 0.f, dN2L = 0.f;   // R[0,0]=0 -> e=1

  const int Bl = w, Bh = w + 8;        // active bursts for this wave

  // current-burst D window: 17 quads covering floats [4*((64B-t)>>2), +68)
  float4 r0,r1,r2,r3,r4,r5,r6,r7,r8,r9,r10,r11,r12,r13,r14,r15,r16;
  {
    const int q = (K * Bl - t) >> 2;
    r0 = Drow4[qclamp(q + 0)];  r1 = Drow4[qclamp(q + 1)];
    r2 = Drow4[qclamp(q + 2)];  r3 = Drow4[qclamp(q + 3)];
    r4 = Drow4[qclamp(q + 4)];  r5 = Drow4[qclamp(q + 5)];
    r6 = Drow4[qclamp(q + 6)];  r7 = Drow4[qclamp(q + 7)];
    r8 = Drow4[qclamp(q + 8)];  r9 = Drow4[qclamp(q + 9)];
    r10 = Drow4[qclamp(q + 10)]; r11 = Drow4[qclamp(q + 11)];
    r12 = Drow4[qclamp(q + 12)]; r13 = Drow4[qclamp(q + 13)];
    r14 = Drow4[qclamp(q + 14)]; r15 = Drow4[qclamp(q + 15)];
    r16 = Drow4[qclamp(q + 16)];
  }
  __syncthreads();

  for (int p = 0; p < PHASES; ++p) {
    const int B = p - w;
    const int Bn = B + 1;
    const bool dopre = (Bn >= Bl) && (Bn <= Bh);   // wave-uniform

    if (B >= Bl && B <= Bh) {
      const int d0 = 2 + B * K;
      const int c0 = K * B - t;        // column base (c = j-1); in [-63, 512]

      const float4* ep = (w > 0)
          ? (const float4*)&edge[w - 1][64 + K * (B - w)]
          : (const float4*)zpad;

      // group a (steps 0..7): LDS latency hides under funnel A
      const float4 na0 = ep[0], na1 = ep[1], na2 = ep[2], na3 = ep[3];

      // ---- funnel A: g_e = D[c0+e], e in [0,32), from quads r0..r8
      const int s = c0 & 3;
      const bool s2 = (s & 2) != 0, s1b = (s & 1) != 0;
      const float
        f0 = r0.x, f1 = r0.y, f2 = r0.z, f3 = r0.w,
        f4 = r1.x, f5 = r1.y, f6 = r1.z, f7 = r1.w,
        f8 = r2.x, f9 = r2.y, f10 = r2.z, f11 = r2.w,
        f12 = r3.x, f13 = r3.y, f14 = r3.z, f15 = r3.w,
        f16 = r4.x, f17 = r4.y, f18 = r4.z, f19 = r4.w,
        f20 = r5.x, f21 = r5.y, f22 = r5.z, f23 = r5.w,
        f24 = r6.x, f25 = r6.y, f26 = r6.z, f27 = r6.w,
        f28 = r7.x, f29 = r7.y, f30 = r7.z, f31 = r7.w,
        f32 = r8.x, f33 = r8.y, f34 = r8.z;
      const float
        x0  = s2 ? f2  : f0,  x1  = s2 ? f3  : f1,  x2  = s2 ? f4  : f2,
        x3  = s2 ? f5  : f3,  x4  = s2 ? f6  : f4,  x5  = s2 ? f7  : f5,
        x6  = s2 ? f8  : f6,  x7  = s2 ? f9  : f7,  x8  = s2 ? f10 : f8,
        x9  = s2 ? f11 : f9,  x10 = s2 ? f12 : f10, x11 = s2 ? f13 : f11,
        x12 = s2 ? f14 : f12, x13 = s2 ? f15 : f13, x14 = s2 ? f16 : f14,
        x15 = s2 ? f17 : f15, x16 = s2 ? f18 : f16, x17 = s2 ? f19 : f17,
        x18 = s2 ? f20 : f18, x19 = s2 ? f21 : f19, x20 = s2 ? f22 : f20,
        x21 = s2 ? f23 : f21, x22 = s2 ? f24 : f22, x23 = s2 ? f25 : f23,
        x24 = s2 ? f26 : f24, x25 = s2 ? f27 : f25, x26 = s2 ? f28 : f26,
        x27 = s2 ? f29 : f27, x28 = s2 ? f30 : f28, x29 = s2 ? f31 : f29,
        x30 = s2 ? f32 : f30, x31 = s2 ? f33 : f31, x32 = s2 ? f34 : f32;
      const float
        g0  = s1b ? x1  : x0,  g1  = s1b ? x2  : x1,  g2  = s1b ? x3  : x2,
        g3  = s1b ? x4  : x3,  g4  = s1b ? x5  : x4,  g5  = s1b ? x6  : x5,
        g6  = s1b ? x7  : x6,  g7  = s1b ? x8  : x7,  g8  = s1b ? x9  : x8,
        g9  = s1b ? x10 : x9,  g10 = s1b ? x11 : x10, g11 = s1b ? x12 : x11,
        g12 = s1b ? x13 : x12, g13 = s1b ? x14 : x13, g14 = s1b ? x15 : x14,
        g15 = s1b ? x16 : x15, g16 = s1b ? x17 : x16, g17 = s1b ? x18 : x17,
        g18 = s1b ? x19 : x18, g19 = s1b ? x20 : x19, g20 = s1b ? x21 : x20,
        g21 = s1b ? x22 : x21, g22 = s1b ? x23 : x22, g23 = s1b ? x24 : x23,
        g24 = s1b ? x25 : x24, g25 = s1b ? x26 : x25, g26 = s1b ? x27 : x26,
        g27 = s1b ? x28 : x27, g28 = s1b ? x29 : x28, g29 = s1b ? x30 : x29,
        g30 = s1b ? x31 : x30, g31 = s1b ? x32 : x31;

      // ---- r0..r7 are dead (funnel A done; r8 still feeds funnel B):
      // issue next burst's first 8 quads now. 32 steps + funnel B + 32
      // steps + barrier of hiding distance.
      if (dopre) {
        const int q = (K * Bn - t) >> 2;
        r0 = Drow4[qclamp(q + 0)];  r1 = Drow4[qclamp(q + 1)];
        r2 = Drow4[qclamp(q + 2)];  r3 = Drow4[qclamp(q + 3)];
        r4 = Drow4[qclamp(q + 4)];  r5 = Drow4[qclamp(q + 5)];
        r6 = Drow4[qclamp(q + 6)];  r7 = Drow4[qclamp(q + 7)];
      }

      // group b (steps 8..15)
      const float4 nb0 = ep[4], nb1 = ep[5], nb2 = ep[6], nb3 = ep[7];

      float2* eput = &edge[w][64 + c0];   // write-once publish (8B stride)

#define STEP(kk, NE, ND, G)                                                    \
      {                                                                        \
        const int c = c0 + (kk);                                               \
        const bool valid = ((unsigned)c) < 512u;                               \
        const float ddL = (G) * NL2E;                                          \
        const float ddLm = valid ? ddL : -1e30f;                               \
        const float sE = lane_shr1_or((NE), eSelf);                            \
        const float sD = lane_shr1_or((ND), dSelfL);                           \
        const float e0 = eN2, e2 = eSelf;                                      \
        const float s02 = (e0 + e2) + EPS;                                     \
        const float sum = s02 + sE;                                            \
        const float inv = __builtin_amdgcn_rcpf(sum);                          \
        const float numL = fmaf(e0, dN2L, fmaf(sE, sD, e2 * dSelfL));          \
        const float rr = fmaf(inv, numL, ddLm);                                \
        const float newE = __builtin_amdgcn_exp2f(rr);                         \
        if (d0 + (kk) == NM && t == N - 1) {                                   \
          const float* Sb = Sig + (size_t)b * N * M;                           \
          const float sgA = Sb[(size_t)(N - 1) * M + (M - 1)];                 \
          const float sg0 = Sb[(size_t)(N - 2) * M + (M - 2)];                 \
          const float sg1 = Sb[(size_t)(N - 2) * M + (M - 1)];                 \
          const float sg2 = Sb[(size_t)(N - 1) * M + (M - 2)];                 \
          out[b] = rr * NLN2;                                                  \
          out[BATCH + b] = sgA + inv * (e0 * sg0 + sE * sg1 + e2 * sg2);       \
        }                                                                      \
        eN2 = sE; dN2L = sD;                                                   \
        eSelf = newE; dSelfL = ddL;                                            \
        eput[kk] = make_float2(newE, ddL);                                     \
      }

      STEP(0,  na0.x, na0.y, g0)  STEP(1,  na0.z, na0.w, g1)
      STEP(2,  na1.x, na1.y, g2)  STEP(3,  na1.z, na1.w, g3)
      STEP(4,  na2.x, na2.y, g4)  STEP(5,  na2.z, na2.w, g5)
      STEP(6,  na3.x, na3.y, g6)  STEP(7,  na3.z, na3.w, g7)

      // group c (steps 16..23)
      const float4 nc0 = ep[8], nc1 = ep[9], nc2 = ep[10], nc3 = ep[11];

      STEP(8,  nb0.x, nb0.y, g8)  STEP(9,  nb0.z, nb0.w, g9)
      STEP(10, nb1.x, nb1.y, g10) STEP(11, nb1.z, nb1.w, g11)
      STEP(12, nb2.x, nb2.y, g12) STEP(13, nb2.z, nb2.w, g13)
      STEP(14, nb3.x, nb3.y, g14) STEP(15, nb3.z, nb3.w, g15)

      // group d (steps 24..31)
      const float4 nd0 = ep[12], nd1 = ep[13], nd2 = ep[14], nd3 = ep[15];

      STEP(16, nc0.x, nc0.y, g16) STEP(17, nc0.z, nc0.w, g17)
      STEP(18, nc1.x, nc1.y, g18) STEP(19, nc1.z, nc1.w, g19)
      STEP(20, nc2.x, nc2.y, g20) STEP(21, nc2.z, nc2.w, g21)
      STEP(22, nc3.x, nc3.y, g22) STEP(23, nc3.z, nc3.w, g23)

      // group e (steps 32..39): read before funnel B so latency hides there
      const float4 ne0 = ep[16], ne1 = ep[17], ne2 = ep[18], ne3 = ep[19];

      STEP(24, nd0.x, nd0.y, g24) STEP(25, nd0.z, nd0.w, g25)
      STEP(26, nd1.x, nd1.y, g26) STEP(27, nd1.z, nd1.w, g27)
      STEP(28, nd2.x, nd2.y, g28) STEP(29, nd2.z, nd2.w, g29)
      STEP(30, nd3.x, nd3.y, g30) STEP(31, nd3.z, nd3.w, g31)

      // ---- funnel B: j_e = D[c0+32+e], e in [0,32), from quads r8..r16
      const float
        h0 = r8.x,  h1 = r8.y,  h2 = r8.z,  h3 = r8.w,
        h4 = r9.x,  h5 = r9.y,  h6 = r9.z,  h7 = r9.w,
        h8 = r10.x, h9 = r10.y, h10 = r10.z, h11 = r10.w,
        h12 = r11.x, h13 = r11.y, h14 = r11.z, h15 = r11.w,
        h16 = r12.x, h17 = r12.y, h18 = r12.z, h19 = r12.w,
        h20 = r13.x, h21 = r13.y, h22 = r13.z, h23 = r13.w,
        h24 = r14.x, h25 = r14.y, h26 = r14.z, h27 = r14.w,
        h28 = r15.x, h29 = r15.y, h30 = r15.z, h31 = r15.w,
        h32 = r16.x, h33 = r16.y, h34 = r16.z;
      const float
        y0  = s2 ? h2  : h0,  y1  = s2 ? h3  : h1,  y2  = s2 ? h4  : h2,
        y3  = s2 ? h5  : h3,  y4  = s2 ? h6  : h4,  y5  = s2 ? h7  : h5,
        y6  = s2 ? h8  : h6,  y7  = s2 ? h9  : h7,  y8  = s2 ? h10 : h8,
        y9  = s2 ? h11 : h9,  y10 = s2 ? h12 : h10, y11 = s2 ? h13 : h11,
        y12 = s2 ? h14 : h12, y13 = s2 ? h15 : h13, y14 = s2 ? h16 : h14,
        y15 = s2 ? h17 : h15, y16 = s2 ? h18 : h16, y17 = s2 ? h19 : h17,
        y18 = s2 ? h20 : h18, y19 = s2 ? h21 : h19, y20 = s2 ? h22 : h20,
        y21 = s2 ? h23 : h21, y22 = s2 ? h24 : h22, y23 = s2 ? h25 : h23,
        y24 = s2 ? h26 : h24, y25 = s2 ? h27 : h25, y26 = s2 ? h28 : h26,
        y27 = s2 ? h29 : h27, y28 = s2 ? h30 : h28, y29 = s2 ? h31 : h29,
        y30 = s2 ? h32 : h30, y31 = s2 ? h33 : h31, y32 = s2 ? h34 : h32;
      const float
        j0  = s1b ? y1  : y0,  j1  = s1b ? y2  : y1,  j2  = s1b ? y3  : y2,
        j3  = s1b ? y4  : y3,  j4  = s1b ? y5  : y4,  j5  = s1b ? y6  : y5,
        j6  = s1b ? y7  : y6,  j7  = s1b ? y8  : y7,  j8  = s1b ? y9  : y8,
        j9  = s1b ? y10 : y9,  j10 = s1b ? y11 : y10, j11 = s1b ? y12 : y11,
        j12 = s1b ? y13 : y12, j13 = s1b ? y14 : y13, j14 = s1b ? y15 : y14,
        j15 = s1b ? y16 : y15, j16 = s1b ? y17 : y16, j17 = s1b ? y18 : y17,
        j18 = s1b ? y19 : y18, j19 = s1b ? y20 : y19, j20 = s1b ? y21 : y20,
        j21 = s1b ? y22 : y21, j22 = s1b ? y23 : y22, j23 = s1b ? y24 : y23,
        j24 = s1b ? y25 : y24, j25 = s1b ? y26 : y25, j26 = s1b ? y27 : y26,
        j27 = s1b ? y28 : y27, j28 = s1b ? y29 : y28, j29 = s1b ? y30 : y29,
        j30 = s1b ? y31 : y30, j31 = s1b ? y32 : y31;

      // ---- r8..r16 dead now: issue next burst's remaining 9 quads; loads
      // cross the lgkm-only barrier and wait at next phase's funnel B.
      if (dopre) {
        const int q = (K * Bn - t) >> 2;
        r8 = Drow4[qclamp(q + 8)];   r9 = Drow4[qclamp(q + 9)];
        r10 = Drow4[qclamp(q + 10)]; r11 = Drow4[qclamp(q + 11)];
        r12 = Drow4[qclamp(q + 12)]; r13 = Drow4[qclamp(q + 13)];
        r14 = Drow4[qclamp(q + 14)]; r15 = Drow4[qclamp(q + 15)];
        r16 = Drow4[qclamp(q + 16)];
      }

      // group f (steps 40..47)
      const float4 nf0 = ep[20], nf1 = ep[21], nf2 = ep[22], nf3 = ep[23];

      STEP(32, ne0.x, ne0.y, j0)  STEP(33, ne0.z, ne0.w, j1)
      STEP(34, ne1.x, ne1.y, j2)  STEP(35, ne1.z, ne1.w, j3)
      STEP(36, ne2.x, ne2.y, j4)  STEP(37, ne2.z, ne2.w, j5)
      STEP(38, ne3.x, ne3.y, j6)  STEP(39, ne3.z, ne3.w, j7)

      // group g (steps 48..55)
      const float4 ng0 = ep[24], ng1 = ep[25], ng2 = ep[26], ng3 = ep[27];

      STEP(40, nf0.x, nf0.y, j8)  STEP(41, nf0.z, nf0.w, j9)
      STEP(42, nf1.x, nf1.y, j10) STEP(43, nf1.z, nf1.w, j11)
      STEP(44, nf2.x, nf2.y, j12) STEP(45, nf2.z, nf2.w, j13)
      STEP(46, nf3.x, nf3.y, j14) STEP(47, nf3.z, nf3.w, j15)

      // group h (steps 56..63)
      const float4 nh0 = ep[28], nh1 = ep[29], nh2 = ep[30], nh3 = ep[31];

      STEP(48, ng0.x, ng0.y, j16) STEP(49, ng0.z, ng0.w, j17)
      STEP(50, ng1.x, ng1.y, j18) STEP(51, ng1.z, ng1.w, j19)
      STEP(52, ng2.x, ng2.y, j20) STEP(53, ng2.z, ng2.w, j21)
      STEP(54, ng3.x, ng3.y, j22) STEP(55, ng3.z, ng3.w, j23)

      STEP(56, nh0.x, nh0.y, j24) STEP(57, nh0.z, nh0.w, j25)
      STEP(58, nh1.x, nh1.y, j26) STEP(59, nh1.z, nh1.w, j27)
      STEP(60, nh2.x, nh2.y, j28) STEP(61, nh2.z, nh2.w, j29)
      STEP(62, nh3.x, nh3.y, j30) STEP(63, nh3.z, nh3.w, j31)
#undef STEP
    } else if (dopre) {
      // pipeline-fill: wave becomes active next phase; load its first burst
      const int q = (K * Bn - t) >> 2;
      r0 = Drow4[qclamp(q + 0)];  r1 = Drow4[qclamp(q + 1)];
      r2 = Drow4[qclamp(q + 2)];  r3 = Drow4[qclamp(q + 3)];
      r4 = Drow4[qclamp(q + 4)];  r5 = Drow4[qclamp(q + 5)];
      r6 = Drow4[qclamp(q + 6)];  r7 = Drow4[qclamp(q + 7)];
      r8 = Drow4[qclamp(q + 8)];  r9 = Drow4[qclamp(q + 9)];
      r10 = Drow4[qclamp(q + 10)]; r11 = Drow4[qclamp(q + 11)];
      r12 = Drow4[qclamp(q + 12)]; r13 = Drow4[qclamp(q + 13)];
      r14 = Drow4[qclamp(q + 14)]; r15 = Drow4[qclamp(q + 15)];
      r16 = Drow4[qclamp(q + 16)];
    }

    // lgkm-only barrier: LDS publishes drained; private global prefetches
    // legally stay in flight across the barrier (counted-vmcnt pattern).
    asm volatile("s_waitcnt lgkmcnt(0)" ::: "memory");
    __builtin_amdgcn_s_barrier();
  }
}

extern "C" void kernel_launch(void* const* d_in, const int* in_sizes, int n_in,
                              void* d_out, int out_size, void* d_ws, size_t ws_size,
                              hipStream_t stream) {
  const float* D   = (const float*)d_in[0];
  const float* Sig = (const float*)d_in[1];
  float* out = (float*)d_out;
  softdtw_fwd<<<dim3(BATCH), dim3(512), 0, stream>>>(D, Sig, out);
}

// Round 9
// 169.199 us; speedup vs baseline: 1.9859x; 1.0175x over previous
//
#include <hip/hip_runtime.h>

// uDTW forward DP, R17 = R16 (K=64, 23 phases, scalar funnels — 107us,
// clean counters) with the global barrier replaced by adjacent-wave
// LDS flag sync.
//
// Model from R14/R16: T = PHASES*(F + steps*s), s~119cyc, F~3.6k/phase
// (barrier skew + drain). K=128 would LOSE (fill/drain grows: -8F+448s>0),
// so attack F: the only cross-wave dep is wave w-1 -> wave w, one phase
// earlier; overwrite margin holds for ANY lead (producer k>=1 phases ahead
// writes columns >= read_base+65). So: per-wave monotone phase counters.
//   producer: s_waitcnt lgkmcnt(0); flags[w] = p+1   (one lane)
//   consumer: spin until flags[w-1] >= p, then compiler memory fence.
// Deadlock-free (monotone, wave 0 never waits). Waves self-time; barrier
// skew is absorbed instead of synchronized.

constexpr int N = 512;
constexpr int M = 512;
constexpr int BATCH = 32;
constexpr int NM = N + M;                  // 1024; diags d = 2..NM
constexpr int K = 64;                      // diagonals per burst
constexpr int NB = 16;                     // bursts cover d = 2..1025
constexpr int PHASES = 23;                 // p = B + w; B in [w, w+8]
constexpr float NL2E = -1.4426950408889634f;   // -log2(e)
constexpr float NLN2 = -0.6931471805599453f;   // -ln(2)
constexpr float EPS  = 1e-30f;

__device__ __forceinline__ float lane_shr1_or(float oldv, float x) {
  // lane n gets lane n-1's x; lane 0 keeps oldv (bound_ctrl=false).
  return __int_as_float(__builtin_amdgcn_update_dpp(
      __float_as_int(oldv), __float_as_int(x), 0x138, 0xf, 0xf, false));
}
__device__ __forceinline__ int qclamp(int q) {
  return q < 0 ? 0 : (q > 127 ? 127 : q);
}

__global__ __launch_bounds__(512, 2)
void softdtw_fwd(const float* __restrict__ D,
                 const float* __restrict__ Sig,
                 float* __restrict__ out) {
  const int b = blockIdx.x;
  const int t = threadIdx.x;           // row r = t, cell i = t+1
  const int w = t >> 6;                // wave 0..7
  const float4* Drow4 = (const float4*)(D + ((size_t)b * N + t) * M);

  // edge[w][64 + c] = (exp(-R), NL2E*Ddiag) of row 64w+63 at column c.
  __shared__ float2 edge[8][640];
  __shared__ __align__(16) float zpad[128];  // zero source for w==0 (32 quads)
  __shared__ int flags[8];                   // completed-phase counters
  for (int idx = t; idx < 8 * 640; idx += 512)
    ((float2*)edge)[idx] = make_float2(0.f, 0.f);
  if (t < 128) zpad[t] = 0.f;
  if (t < 8) flags[t] = 0;

  // carried state: own cell at d-1, neighbor (i-1) at d-2 (D pre-scaled)
  float eSelf = 0.f, dSelfL = 0.f;
  float eN2 = (t == 0) ? 1.f : 0.f, dN2L = 0.f;   // R[0,0]=0 -> e=1

  const int Bl = w, Bh = w + 8;        // active bursts for this wave

  // current-burst D window: 17 quads covering floats [4*((64B-t)>>2), +68)
  float4 r0,r1,r2,r3,r4,r5,r6,r7,r8,r9,r10,r11,r12,r13,r14,r15,r16;
  {
    const int q = (K * Bl - t) >> 2;
    r0 = Drow4[qclamp(q + 0)];  r1 = Drow4[qclamp(q + 1)];
    r2 = Drow4[qclamp(q + 2)];  r3 = Drow4[qclamp(q + 3)];
    r4 = Drow4[qclamp(q + 4)];  r5 = Drow4[qclamp(q + 5)];
    r6 = Drow4[qclamp(q + 6)];  r7 = Drow4[qclamp(q + 7)];
    r8 = Drow4[qclamp(q + 8)];  r9 = Drow4[qclamp(q + 9)];
    r10 = Drow4[qclamp(q + 10)]; r11 = Drow4[qclamp(q + 11)];
    r12 = Drow4[qclamp(q + 12)]; r13 = Drow4[qclamp(q + 13)];
    r14 = Drow4[qclamp(q + 14)]; r15 = Drow4[qclamp(q + 15)];
    r16 = Drow4[qclamp(q + 16)];
  }
  __syncthreads();   // once: zero-init + flags visible to all waves

  for (int p = 0; p < PHASES; ++p) {
    const int B = p - w;
    const int Bn = B + 1;
    const bool dopre = (Bn >= Bl) && (Bn <= Bh);   // wave-uniform

    if (B >= Bl && B <= Bh) {
      const int d0 = 2 + B * K;
      const int c0 = K * B - t;        // column base (c = j-1); in [-63, 512]

      // ---- wait for producer (wave w-1) to have completed phase p-1;
      // then fence so the ep reads below cannot be hoisted above the spin.
      if (w > 0) {
        while (*(volatile int*)&flags[w - 1] < p)
          __builtin_amdgcn_s_sleep(1);
        asm volatile("" ::: "memory");
      }

      const float4* ep = (w > 0)
          ? (const float4*)&edge[w - 1][64 + K * (B - w)]
          : (const float4*)zpad;

      // group a (steps 0..7): LDS latency hides under funnel A
      const float4 na0 = ep[0], na1 = ep[1], na2 = ep[2], na3 = ep[3];

      // ---- funnel A: g_e = D[c0+e], e in [0,32), from quads r0..r8
      const int s = c0 & 3;
      const bool s2 = (s & 2) != 0, s1b = (s & 1) != 0;
      const float
        f0 = r0.x, f1 = r0.y, f2 = r0.z, f3 = r0.w,
        f4 = r1.x, f5 = r1.y, f6 = r1.z, f7 = r1.w,
        f8 = r2.x, f9 = r2.y, f10 = r2.z, f11 = r2.w,
        f12 = r3.x, f13 = r3.y, f14 = r3.z, f15 = r3.w,
        f16 = r4.x, f17 = r4.y, f18 = r4.z, f19 = r4.w,
        f20 = r5.x, f21 = r5.y, f22 = r5.z, f23 = r5.w,
        f24 = r6.x, f25 = r6.y, f26 = r6.z, f27 = r6.w,
        f28 = r7.x, f29 = r7.y, f30 = r7.z, f31 = r7.w,
        f32 = r8.x, f33 = r8.y, f34 = r8.z;
      const float
        x0  = s2 ? f2  : f0,  x1  = s2 ? f3  : f1,  x2  = s2 ? f4  : f2,
        x3  = s2 ? f5  : f3,  x4  = s2 ? f6  : f4,  x5  = s2 ? f7  : f5,
        x6  = s2 ? f8  : f6,  x7  = s2 ? f9  : f7,  x8  = s2 ? f10 : f8,
        x9  = s2 ? f11 : f9,  x10 = s2 ? f12 : f10, x11 = s2 ? f13 : f11,
        x12 = s2 ? f14 : f12, x13 = s2 ? f15 : f13, x14 = s2 ? f16 : f14,
        x15 = s2 ? f17 : f15, x16 = s2 ? f18 : f16, x17 = s2 ? f19 : f17,
        x18 = s2 ? f20 : f18, x19 = s2 ? f21 : f19, x20 = s2 ? f22 : f20,
        x21 = s2 ? f23 : f21, x22 = s2 ? f24 : f22, x23 = s2 ? f25 : f23,
        x24 = s2 ? f26 : f24, x25 = s2 ? f27 : f25, x26 = s2 ? f28 : f26,
        x27 = s2 ? f29 : f27, x28 = s2 ? f30 : f28, x29 = s2 ? f31 : f29,
        x30 = s2 ? f32 : f30, x31 = s2 ? f33 : f31, x32 = s2 ? f34 : f32;
      const float
        g0  = s1b ? x1  : x0,  g1  = s1b ? x2  : x1,  g2  = s1b ? x3  : x2,
        g3  = s1b ? x4  : x3,  g4  = s1b ? x5  : x4,  g5  = s1b ? x6  : x5,
        g6  = s1b ? x7  : x6,  g7  = s1b ? x8  : x7,  g8  = s1b ? x9  : x8,
        g9  = s1b ? x10 : x9,  g10 = s1b ? x11 : x10, g11 = s1b ? x12 : x11,
        g12 = s1b ? x13 : x12, g13 = s1b ? x14 : x13, g14 = s1b ? x15 : x14,
        g15 = s1b ? x16 : x15, g16 = s1b ? x17 : x16, g17 = s1b ? x18 : x17,
        g18 = s1b ? x19 : x18, g19 = s1b ? x20 : x19, g20 = s1b ? x21 : x20,
        g21 = s1b ? x22 : x21, g22 = s1b ? x23 : x22, g23 = s1b ? x24 : x23,
        g24 = s1b ? x25 : x24, g25 = s1b ? x26 : x25, g26 = s1b ? x27 : x26,
        g27 = s1b ? x28 : x27, g28 = s1b ? x29 : x28, g29 = s1b ? x30 : x29,
        g30 = s1b ? x31 : x30, g31 = s1b ? x32 : x31;

      // ---- r0..r7 are dead (funnel A done; r8 still feeds funnel B):
      // issue next burst's first 8 quads now.
      if (dopre) {
        const int q = (K * Bn - t) >> 2;
        r0 = Drow4[qclamp(q + 0)];  r1 = Drow4[qclamp(q + 1)];
        r2 = Drow4[qclamp(q + 2)];  r3 = Drow4[qclamp(q + 3)];
        r4 = Drow4[qclamp(q + 4)];  r5 = Drow4[qclamp(q + 5)];
        r6 = Drow4[qclamp(q + 6)];  r7 = Drow4[qclamp(q + 7)];
      }

      // group b (steps 8..15)
      const float4 nb0 = ep[4], nb1 = ep[5], nb2 = ep[6], nb3 = ep[7];

      float2* eput = &edge[w][64 + c0];   // write-once publish (8B stride)

#define STEP(kk, NE, ND, G)                                                    \
      {                                                                        \
        const int c = c0 + (kk);                                               \
        const bool valid = ((unsigned)c) < 512u;                               \
        const float ddL = (G) * NL2E;                                          \
        const float ddLm = valid ? ddL : -1e30f;                               \
        const float sE = lane_shr1_or((NE), eSelf);                            \
        const float sD = lane_shr1_or((ND), dSelfL);                           \
        const float e0 = eN2, e2 = eSelf;                                      \
        const float s02 = (e0 + e2) + EPS;                                     \
        const float sum = s02 + sE;                                            \
        const float inv = __builtin_amdgcn_rcpf(sum);                          \
        const float numL = fmaf(e0, dN2L, fmaf(sE, sD, e2 * dSelfL));          \
        const float rr = fmaf(inv, numL, ddLm);                                \
        const float newE = __builtin_amdgcn_exp2f(rr);                         \
        if (d0 + (kk) == NM && t == N - 1) {                                   \
          const float* Sb = Sig + (size_t)b * N * M;                           \
          const float sgA = Sb[(size_t)(N - 1) * M + (M - 1)];                 \
          const float sg0 = Sb[(size_t)(N - 2) * M + (M - 2)];                 \
          const float sg1 = Sb[(size_t)(N - 2) * M + (M - 1)];                 \
          const float sg2 = Sb[(size_t)(N - 1) * M + (M - 2)];                 \
          out[b] = rr * NLN2;                                                  \
          out[BATCH + b] = sgA + inv * (e0 * sg0 + sE * sg1 + e2 * sg2);       \
        }                                                                      \
        eN2 = sE; dN2L = sD;                                                   \
        eSelf = newE; dSelfL = ddL;                                            \
        eput[kk] = make_float2(newE, ddL);                                     \
      }

      STEP(0,  na0.x, na0.y, g0)  STEP(1,  na0.z, na0.w, g1)
      STEP(2,  na1.x, na1.y, g2)  STEP(3,  na1.z, na1.w, g3)
      STEP(4,  na2.x, na2.y, g4)  STEP(5,  na2.z, na2.w, g5)
      STEP(6,  na3.x, na3.y, g6)  STEP(7,  na3.z, na3.w, g7)

      // group c (steps 16..23)
      const float4 nc0 = ep[8], nc1 = ep[9], nc2 = ep[10], nc3 = ep[11];

      STEP(8,  nb0.x, nb0.y, g8)  STEP(9,  nb0.z, nb0.w, g9)
      STEP(10, nb1.x, nb1.y, g10) STEP(11, nb1.z, nb1.w, g11)
      STEP(12, nb2.x, nb2.y, g12) STEP(13, nb2.z, nb2.w, g13)
      STEP(14, nb3.x, nb3.y, g14) STEP(15, nb3.z, nb3.w, g15)

      // group d (steps 24..31)
      const float4 nd0 = ep[12], nd1 = ep[13], nd2 = ep[14], nd3 = ep[15];

      STEP(16, nc0.x, nc0.y, g16) STEP(17, nc0.z, nc0.w, g17)
      STEP(18, nc1.x, nc1.y, g18) STEP(19, nc1.z, nc1.w, g19)
      STEP(20, nc2.x, nc2.y, g20) STEP(21, nc2.z, nc2.w, g21)
      STEP(22, nc3.x, nc3.y, g22) STEP(23, nc3.z, nc3.w, g23)

      // group e (steps 32..39): read before funnel B so latency hides there
      const float4 ne0 = ep[16], ne1 = ep[17], ne2 = ep[18], ne3 = ep[19];

      STEP(24, nd0.x, nd0.y, g24) STEP(25, nd0.z, nd0.w, g25)
      STEP(26, nd1.x, nd1.y, g26) STEP(27, nd1.z, nd1.w, g27)
      STEP(28, nd2.x, nd2.y, g28) STEP(29, nd2.z, nd2.w, g29)
      STEP(30, nd3.x, nd3.y, g30) STEP(31, nd3.z, nd3.w, g31)

      // ---- funnel B: j_e = D[c0+32+e], e in [0,32), from quads r8..r16
      const float
        h0 = r8.x,  h1 = r8.y,  h2 = r8.z,  h3 = r8.w,
        h4 = r9.x,  h5 = r9.y,  h6 = r9.z,  h7 = r9.w,
        h8 = r10.x, h9 = r10.y, h10 = r10.z, h11 = r10.w,
        h12 = r11.x, h13 = r11.y, h14 = r11.z, h15 = r11.w,
        h16 = r12.x, h17 = r12.y, h18 = r12.z, h19 = r12.w,
        h20 = r13.x, h21 = r13.y, h22 = r13.z, h23 = r13.w,
        h24 = r14.x, h25 = r14.y, h26 = r14.z, h27 = r14.w,
        h28 = r15.x, h29 = r15.y, h30 = r15.z, h31 = r15.w,
        h32 = r16.x, h33 = r16.y, h34 = r16.z;
      const float
        y0  = s2 ? h2  : h0,  y1  = s2 ? h3  : h1,  y2  = s2 ? h4  : h2,
        y3  = s2 ? h5  : h3,  y4  = s2 ? h6  : h4,  y5  = s2 ? h7  : h5,
        y6  = s2 ? h8  : h6,  y7  = s2 ? h9  : h7,  y8  = s2 ? h10 : h8,
        y9  = s2 ? h11 : h9,  y10 = s2 ? h12 : h10, y11 = s2 ? h13 : h11,
        y12 = s2 ? h14 : h12, y13 = s2 ? h15 : h13, y14 = s2 ? h16 : h14,
        y15 = s2 ? h17 : h15, y16 = s2 ? h18 : h16, y17 = s2 ? h19 : h17,
        y18 = s2 ? h20 : h18, y19 = s2 ? h21 : h19, y20 = s2 ? h22 : h20,
        y21 = s2 ? h23 : h21, y22 = s2 ? h24 : h22, y23 = s2 ? h25 : h23,
        y24 = s2 ? h26 : h24, y25 = s2 ? h27 : h25, y26 = s2 ? h28 : h26,
        y27 = s2 ? h29 : h27, y28 = s2 ? h30 : h28, y29 = s2 ? h31 : h29,
        y30 = s2 ? h32 : h30, y31 = s2 ? h33 : h31, y32 = s2 ? h34 : h32;
      const float
        j0  = s1b ? y1  : y0,  j1  = s1b ? y2  : y1,  j2  = s1b ? y3  : y2,
        j3  = s1b ? y4  : y3,  j4  = s1b ? y5  : y4,  j5  = s1b ? y6  : y5,
        j6  = s1b ? y7  : y6,  j7  = s1b ? y8  : y7,  j8  = s1b ? y9  : y8,
        j9  = s1b ? y10 : y9,  j10 = s1b ? y11 : y10, j11 = s1b ? y12 : y11,
        j12 = s1b ? y13 : y12, j13 = s1b ? y14 : y13, j14 = s1b ? y15 : y14,
        j15 = s1b ? y16 : y15, j16 = s1b ? y17 : y16, j17 = s1b ? y18 : y17,
        j18 = s1b ? y19 : y18, j19 = s1b ? y20 : y19, j20 = s1b ? y21 : y20,
        j21 = s1b ? y22 : y21, j22 = s1b ? y23 : y22, j23 = s1b ? y24 : y23,
        j24 = s1b ? y25 : y24, j25 = s1b ? y26 : y25, j26 = s1b ? y27 : y26,
        j27 = s1b ? y28 : y27, j28 = s1b ? y29 : y28, j29 = s1b ? y30 : y29,
        j30 = s1b ? y31 : y30, j31 = s1b ? y32 : y31;

      // ---- r8..r16 dead now: issue next burst's remaining 9 quads; their
      // waits land at next phase's funnel B (no barrier to drain them).
      if (dopre) {
        const int q = (K * Bn - t) >> 2;
        r8 = Drow4[qclamp(q + 8)];   r9 = Drow4[qclamp(q + 9)];
        r10 = Drow4[qclamp(q + 10)]; r11 = Drow4[qclamp(q + 11)];
        r12 = Drow4[qclamp(q + 12)]; r13 = Drow4[qclamp(q + 13)];
        r14 = Drow4[qclamp(q + 14)]; r15 = Drow4[qclamp(q + 15)];
        r16 = Drow4[qclamp(q + 16)];
      }

      // group f (steps 40..47)
      const float4 nf0 = ep[20], nf1 = ep[21], nf2 = ep[22], nf3 = ep[23];

      STEP(32, ne0.x, ne0.y, j0)  STEP(33, ne0.z, ne0.w, j1)
      STEP(34, ne1.x, ne1.y, j2)  STEP(35, ne1.z, ne1.w, j3)
      STEP(36, ne2.x, ne2.y, j4)  STEP(37, ne2.z, ne2.w, j5)
      STEP(38, ne3.x, ne3.y, j6)  STEP(39, ne3.z, ne3.w, j7)

      // group g (steps 48..55)
      const float4 ng0 = ep[24], ng1 = ep[25], ng2 = ep[26], ng3 = ep[27];

      STEP(40, nf0.x, nf0.y, j8)  STEP(41, nf0.z, nf0.w, j9)
      STEP(42, nf1.x, nf1.y, j10) STEP(43, nf1.z, nf1.w, j11)
      STEP(44, nf2.x, nf2.y, j12) STEP(45, nf2.z, nf2.w, j13)
      STEP(46, nf3.x, nf3.y, j14) STEP(47, nf3.z, nf3.w, j15)

      // group h (steps 56..63)
      const float4 nh0 = ep[28], nh1 = ep[29], nh2 = ep[30], nh3 = ep[31];

      STEP(48, ng0.x, ng0.y, j16) STEP(49, ng0.z, ng0.w, j17)
      STEP(50, ng1.x, ng1.y, j18) STEP(51, ng1.z, ng1.w, j19)
      STEP(52, ng2.x, ng2.y, j20) STEP(53, ng2.z, ng2.w, j21)
      STEP(54, ng3.x, ng3.y, j22) STEP(55, ng3.z, ng3.w, j23)

      STEP(56, nh0.x, nh0.y, j24) STEP(57, nh0.z, nh0.w, j25)
      STEP(58, nh1.x, nh1.y, j26) STEP(59, nh1.z, nh1.w, j27)
      STEP(60, nh2.x, nh2.y, j28) STEP(61, nh2.z, nh2.w, j29)
      STEP(62, nh3.x, nh3.y, j30) STEP(63, nh3.z, nh3.w, j31)
#undef STEP
    } else if (dopre) {
      // pipeline-fill: wave becomes active next phase; load its first burst
      const int q = (K * Bn - t) >> 2;
      r0 = Drow4[qclamp(q + 0)];  r1 = Drow4[qclamp(q + 1)];
      r2 = Drow4[qclamp(q + 2)];  r3 = Drow4[qclamp(q + 3)];
      r4 = Drow4[qclamp(q + 4)];  r5 = Drow4[qclamp(q + 5)];
      r6 = Drow4[qclamp(q + 6)];  r7 = Drow4[qclamp(q + 7)];
      r8 = Drow4[qclamp(q + 8)];  r9 = Drow4[qclamp(q + 9)];
      r10 = Drow4[qclamp(q + 10)]; r11 = Drow4[qclamp(q + 11)];
      r12 = Drow4[qclamp(q + 12)]; r13 = Drow4[qclamp(q + 13)];
      r14 = Drow4[qclamp(q + 14)]; r15 = Drow4[qclamp(q + 15)];
      r16 = Drow4[qclamp(q + 16)];
    }

    // ---- publish "phase p done": all LDS edge writes drained first.
    // Replaces the global barrier; consumers spin on flags[w-1].
    asm volatile("s_waitcnt lgkmcnt(0)" ::: "memory");
    if ((t & 63) == 0) *(volatile int*)&flags[w] = p + 1;
  }
}

extern "C" void kernel_launch(void* const* d_in, const int* in_sizes, int n_in,
                              void* d_out, int out_size, void* d_ws, size_t ws_size,
                              hipStream_t stream) {
  const float* D   = (const float*)d_in[0];
  const float* Sig = (const float*)d_in[1];
  float* out = (float*)d_out;
  softdtw_fwd<<<dim3(BATCH), dim3(512), 0, stream>>>(D, Sig, out);
}